// Round 1
// baseline (224.944 us; speedup 1.0000x reference)
//
#include <hip/hip_runtime.h>

// CapsuleNet forward, fully fused, fp32.
// Thread layout (768 threads):
//   t < 720: (o = t/72, i = (t%72)/2, dh = t&1)  -> owns lin_w[o][i][dh*8..dh*8+7][0..7] in regs
//   reduce phase: t < 320 -> (m = t/160, o = (t%160)/16, d = t%16)
//   softmax-sum phase: t < 72 -> (m = t/36, i = t%36)
constexpr int OC = 10, NI = 36, OD = 16, IL = 8;
constexpr int M_BLK   = 16;           // batches per block
constexpr int M_INNER = 2;            // batches per routing pass
constexpr int NGROUPS = M_BLK / M_INNER;
constexpr int NT      = 768;
constexpr int SROW    = 18;           // padded spl row stride (floats) - breaks bank conflicts
constexpr int SPL_SZ  = OC * NI * SROW;   // 6480

__global__ __launch_bounds__(NT, 1)
void capsnet_kernel(const float* __restrict__ xg,
                    const float* __restrict__ cwg,
                    const float* __restrict__ lwg,
                    float* __restrict__ outg) {
    __shared__ float xs[M_BLK * 9];                 // staged input patches
    __shared__ float cw[288];                       // conv weights
    __shared__ float caps_t[IL * M_BLK * NI];       // [l][m*36+i], transposed for conflict-free reads
    __shared__ float spl[M_INNER * SPL_SZ];         // s-partials [m][(o*36+i)*18 + d]
    __shared__ float el[M_INNER * NI * OC];         // exp(logits) [m][i][o]
    __shared__ float sinv[M_INNER * NI];            // 1/sum_o exp
    __shared__ float outl[M_INNER * OC * OD];       // out vectors per routing pass

    const int t  = threadIdx.x;
    const int b0 = blockIdx.x * M_BLK;

    if (t < M_BLK * 9) xs[t] = xg[b0 * 9 + t];
    if (t < 288)       cw[t] = cwg[t];

    const bool act = t < 2 * OC * NI;   // 720
    const int o  = t / (2 * NI);
    const int i  = (t % (2 * NI)) >> 1;
    const int dh = t & 1;

    // lin_w fragment: 64 floats in 16 float4 registers, reused for all 16 batches
    float4 w4[16];
    if (act) {
        const float4* wp = reinterpret_cast<const float4*>(
            lwg + ((o * NI + i) * OD + dh * 8) * IL);
        #pragma unroll
        for (int j = 0; j < 16; ++j) w4[j] = wp[j];
    }
    __syncthreads();

    // ---- conv (1->32ch, 3x3, pad 1) + squash over capsule length -> caps_t ----
    for (int task = t; task < M_BLK * NI; task += NT) {
        const int m  = task / NI;
        const int ci = task % NI;
        const int cg = ci & 3;          // capsule group (channel block of 8)
        const int wx = (ci >> 2) % 3;
        const int hx = ci / 12;
        float acc[IL] = {0.f,0.f,0.f,0.f,0.f,0.f,0.f,0.f};
        #pragma unroll
        for (int kh = 0; kh < 3; ++kh) {
            const int xh = hx + kh - 1;
            if (xh < 0 || xh > 2) continue;
            #pragma unroll
            for (int kw = 0; kw < 3; ++kw) {
                const int xw = wx + kw - 1;
                if (xw < 0 || xw > 2) continue;
                const float xv = xs[m * 9 + xh * 3 + xw];
                #pragma unroll
                for (int l = 0; l < IL; ++l)
                    acc[l] += xv * cw[(cg * 8 + l) * 9 + kh * 3 + kw];
            }
        }
        float n2 = 0.f;
        #pragma unroll
        for (int l = 0; l < IL; ++l) n2 += acc[l] * acc[l];
        const float sc = n2 / (1.f + n2) * rsqrtf(n2 + 1e-8f);
        #pragma unroll
        for (int l = 0; l < IL; ++l)
            caps_t[l * (M_BLK * NI) + task] = acc[l] * sc;
    }
    __syncthreads();

    // ---- per 2-batch group: priors einsum (regs) + 3 routing iterations ----
    for (int grp = 0; grp < NGROUPS; ++grp) {
        float P[M_INNER][8];
        float lg[M_INNER];
        float p[M_INNER];
        float ee[M_INNER];
        if (act) {
            #pragma unroll
            for (int m = 0; m < M_INNER; ++m) {
                float cc[IL];
                #pragma unroll
                for (int l = 0; l < IL; ++l)
                    cc[l] = caps_t[l * (M_BLK * NI) + (grp * M_INNER + m) * NI + i];
                #pragma unroll
                for (int d = 0; d < 8; ++d) {
                    const float4 a  = w4[d * 2];
                    const float4 b4 = w4[d * 2 + 1];
                    P[m][d] = a.x  * cc[0] + a.y  * cc[1] + a.z  * cc[2] + a.w  * cc[3]
                            + b4.x * cc[4] + b4.y * cc[5] + b4.z * cc[6] + b4.w * cc[7];
                }
                lg[m] = 0.f;
            }
        }
        p[0] = 0.1f; p[1] = 0.1f;   // softmax of zero logits over 10 out-capsules

        for (int it = 0; it < 3; ++it) {
            // s-partials into padded LDS
            if (act) {
                #pragma unroll
                for (int m = 0; m < M_INNER; ++m) {
                    float* row = &spl[m * SPL_SZ + (o * NI + i) * SROW + dh * 8];
                    #pragma unroll
                    for (int d = 0; d < 8; d += 2) {
                        float2 v = make_float2(p[m] * P[m][d], p[m] * P[m][d + 1]);
                        *reinterpret_cast<float2*>(row + d) = v;
                    }
                }
            }
            __syncthreads();
            // reduce over i (36), squash over d (shfl width 16), emit out
            if (t < M_INNER * OC * OD) {   // 320
                const int m  = t / (OC * OD);
                const int od = t % (OC * OD);
                const int oo = od / OD;
                const int d  = od % OD;
                const float* col = &spl[m * SPL_SZ + oo * NI * SROW + d];
                float s = 0.f;
                #pragma unroll
                for (int ii = 0; ii < NI; ++ii) s += col[ii * SROW];
                float n2 = s * s;
                n2 += __shfl_xor(n2, 1, 16);
                n2 += __shfl_xor(n2, 2, 16);
                n2 += __shfl_xor(n2, 4, 16);
                n2 += __shfl_xor(n2, 8, 16);
                const float sc = n2 / (1.f + n2) * rsqrtf(n2 + 1e-8f);
                const float ov = s * sc;
                if (it == 2) outg[(b0 + grp * M_INNER + m) * (OC * OD) + od] = ov;
                else         outl[m * (OC * OD) + od] = ov;
            }
            __syncthreads();
            if (it == 2) break;
            // agreement: delta[o][i] = sum_d priors*out ; update logits, exp
            if (act) {
                #pragma unroll
                for (int m = 0; m < M_INNER; ++m) {
                    const float* om = &outl[m * (OC * OD) + o * OD + dh * 8];
                    float dpart = 0.f;
                    #pragma unroll
                    for (int d = 0; d < 8; ++d) dpart += P[m][d] * om[d];
                    const float delta = dpart + __shfl_xor(dpart, 1);
                    lg[m] += delta;
                    ee[m] = __expf(lg[m]);
                    if (dh == 0) el[m * (NI * OC) + i * OC + o] = ee[m];
                }
            }
            __syncthreads();
            // softmax denominator over o per (m,i)
            if (t < M_INNER * NI) {   // 72
                const float* er = &el[(t / NI) * (NI * OC) + (t % NI) * OC];
                float ss = 0.f;
                #pragma unroll
                for (int o2 = 0; o2 < OC; ++o2) ss += er[o2];
                sinv[t] = 1.f / ss;
            }
            __syncthreads();
            if (act) {
                p[0] = ee[0] * sinv[i];
                p[1] = ee[1] * sinv[NI + i];
            }
        }
    }
}

extern "C" void kernel_launch(void* const* d_in, const int* in_sizes, int n_in,
                              void* d_out, int out_size, void* d_ws, size_t ws_size,
                              hipStream_t stream) {
    const float* x  = (const float*)d_in[0];   // [B,1,3,3]
    const float* cw = (const float*)d_in[1];   // [32,1,3,3]
    const float* lw = (const float*)d_in[2];   // [10,36,16,8]
    float* out = (float*)d_out;                // [B,10,16]
    const int B = in_sizes[0] / 9;             // 16384
    dim3 grid(B / M_BLK), block(NT);
    capsnet_kernel<<<grid, block, 0, stream>>>(x, cw, lw, out);
}